// Round 1
// baseline (888.281 us; speedup 1.0000x reference)
//
#include <hip/hip_runtime.h>

// ---- types ----
typedef __bf16 bf16x8 __attribute__((ext_vector_type(8)));
typedef float  floatx4 __attribute__((ext_vector_type(4)));
typedef float  fvec4  __attribute__((ext_vector_type(4)));
typedef unsigned short ushort4v __attribute__((ext_vector_type(4)));

__device__ __forceinline__ unsigned short f2bf(float f) {
  unsigned int u = __float_as_uint(f);
  u = u + 0x7FFFu + ((u >> 16) & 1u);   // RNE
  return (unsigned short)(u >> 16);
}

// ws layout (ushort elems unless noted):
//   0        : WP2 bf16  [29][256][512]
//   3801088  : WP3 bf16  [2][256][768]
//   64 MiB   : Y fp32    [31][16*256][128]
#define WP3_OFF   3801088
#define Y_OFF_B   (64u << 20)

// ---- prep: fp32 -> bf16 weight copies. Layout [o][i][k] == MFMA-B row order.
__global__ __launch_bounds__(256) void prep_kernel(
    const float* __restrict__ w2, const float* __restrict__ w3,
    unsigned short* __restrict__ ws)
{
  int g = blockIdx.x * 256 + threadIdx.x;      // 0 .. 1048575 float4 groups
  const float* src; unsigned short* dst;
  if (g < 950272) { src = w2; dst = ws; }
  else            { g -= 950272; src = w3; dst = ws + WP3_OFF; }
  fvec4 v = *reinterpret_cast<const fvec4*>(src + 4*g);
  ushort4v o;
  o[0] = f2bf(v[0]); o[1] = f2bf(v[1]); o[2] = f2bf(v[2]); o[3] = f2bf(v[3]);
  *reinterpret_cast<ushort4v*>(dst + 4*g) = o;
}

// ---- fused chain: one block per batch, whole 31-layer chain LDS-resident.
// LA holds the current layer's A-matrix, k-major: LA[m][KW*i+kk] = X[i][cs*m+kk],
// row pitch P = 256*KW + 8 elems (rows 16B-aligned; bank stride 4 -> ~2-way).
// Per layer: compute (reads LA) -> sync -> writeback next layout (writes LA) -> sync.

template<int KW, int MTH, int KWN>
__device__ __forceinline__ void step(
    unsigned short* LA, int b, int Lout, int LoutN,
    const unsigned short* __restrict__ W, const float* __restrict__ bias,
    float* __restrict__ Yl, int tid)
{
  constexpr int K   = 256 * KW;
  constexpr int P   = K + 8;
  constexpr int NIT = K / 32;
  constexpr int PN  = (KWN == 3) ? 776 : 520;

  const int wave = tid >> 6, lane = tid & 63;
  const int l15 = lane & 15, quad = lane >> 4;
  const int n0 = (wave >> 1) * 32;     // wave owns channels [n0, n0+32)
  const int mh = wave & 1;             // and half of the m-tiles
  const int nA = n0 + l15, nB = nA + 16;

  const unsigned short* wAp = W + nA * K + quad * 8;
  const unsigned short* wBp = W + nB * K + quad * 8;

  floatx4 acc[2][MTH];
#pragma unroll
  for (int p = 0; p < 2; ++p)
#pragma unroll
    for (int t = 0; t < MTH; ++t) acc[p][t] = (floatx4){0.f, 0.f, 0.f, 0.f};

  int aoff[MTH];
#pragma unroll
  for (int t = 0; t < MTH; ++t)
    aoff[t] = ((mh * MTH + t) * 16 + l15) * P + quad * 8;

#pragma unroll
  for (int kc = 0; kc < NIT; ++kc) {
    bf16x8 bA = *reinterpret_cast<const bf16x8*>(wAp + kc * 32);
    bf16x8 bB = *reinterpret_cast<const bf16x8*>(wBp + kc * 32);
#pragma unroll
    for (int t = 0; t < MTH; ++t) {
      bf16x8 a = *reinterpret_cast<const bf16x8*>(&LA[aoff[t] + kc * 32]);
      acc[0][t] = __builtin_amdgcn_mfma_f32_16x16x32_bf16(a, bA, acc[0][t], 0, 0, 0);
      acc[1][t] = __builtin_amdgcn_mfma_f32_16x16x32_bf16(a, bB, acc[1][t], 0, 0, 0);
    }
  }
  __syncthreads();   // all reads of LA done before any wave overwrites it

  const float bvA = bias[nA], bvB = bias[nB];
#pragma unroll
  for (int p = 0; p < 2; ++p) {
    const int n = p ? nB : nA;
    const float bv = p ? bvB : bvA;
    float* yrow = Yl + (b * 256 + n) * 128;
#pragma unroll
    for (int t = 0; t < MTH; ++t) {
      const int mbase = (mh * MTH + t) * 16 + quad * 4;
      float vs[4];
#pragma unroll
      for (int r = 0; r < 4; ++r) {
        const int m = mbase + r;
        const float v = acc[p][t][r] + bv;
        vs[r] = v;
        if (m < Lout) {
          const unsigned short bf = f2bf(v);
          if (KWN == 2) {
            // next layer: LA[m'][2n+kk] = X[n][m'+kk]
            if (m < LoutN) LA[m * PN + 2 * n]           = bf;
            if (m >= 1)    LA[(m - 1) * PN + 2 * n + 1] = bf;
          } else if (KWN == 3) {
            // next layer (k3,s2): LA[m'][3n+kk] = X[n][2m'+kk]
            if ((m & 1) == 0) {
              if ((m >> 1) < LoutN) LA[(m >> 1) * PN + 3 * n]           = bf;
              if (m >= 2)           LA[((m - 2) >> 1) * PN + 3 * n + 2] = bf;
            } else {
              if ((m >> 1) < LoutN) LA[(m >> 1) * PN + 3 * n + 1]       = bf;
            }
          }
        }
      }
      if (mbase + 4 <= Lout) {
        *reinterpret_cast<fvec4*>(yrow + mbase) = (fvec4){vs[0], vs[1], vs[2], vs[3]};
      } else {
#pragma unroll
        for (int r = 0; r < 4; ++r)
          if (mbase + r < Lout) yrow[mbase + r] = vs[r];
      }
    }
  }
  __syncthreads();   // writeback complete before next layer's reads
}

__global__ __launch_bounds__(1024) void chain_kernel(
    const float* __restrict__ x, const float* __restrict__ b2,
    const float* __restrict__ b3, const unsigned short* __restrict__ wsw,
    float* __restrict__ Y)
{
  __shared__ unsigned short LA[66560];   // 133,120 B: fits layer0 (128 rows x 520)
  const int b   = blockIdx.x;
  const int tid = threadIdx.x;

  // stage layer-0 A-matrix: LA[m][2i+kk] = bf16(x[b][i][m+kk]); lanes walk i
  // (consecutive-lane LDS writes conflict-free; strided global reads hit L2).
  for (int idx = tid; idx < 32768; idx += 1024) {
    const int i = idx & 255, m = idx >> 8;
    const unsigned short bf = f2bf(x[(b * 256 + i) * 128 + m]);
    if (m < 127) LA[m * 520 + 2 * i]           = bf;
    if (m >= 1)  LA[(m - 1) * 520 + 2 * i + 1] = bf;
  }
  __syncthreads();

  const unsigned short* wp2 = wsw;
  const unsigned short* wp3 = wsw + WP3_OFF;

  // group A: 15 x (k2,s1), L 128 -> 113
#pragma unroll 1
  for (int l = 0; l < 14; ++l)
    step<2, 4, 2>(LA, b, 127 - l, 126 - l, wp2 + l * 131072, b2 + l * 256,
                  Y + (long)l * 524288, tid);
  step<2, 4, 3>(LA, b, 113, 56, wp2 + 14 * 131072, b2 + 14 * 256,
                Y + (long)14 * 524288, tid);
  // group B: (k3,s2) then 7 x (k2,s1), L 113 -> 56 -> 49
  step<3, 2, 2>(LA, b, 56, 55, wp3, b3, Y + (long)15 * 524288, tid);
#pragma unroll 1
  for (int l = 16; l < 22; ++l)
    step<2, 2, 2>(LA, b, 71 - l, 70 - l, wp2 + (l - 1) * 131072, b2 + (l - 1) * 256,
                  Y + (long)l * 524288, tid);
  step<2, 2, 3>(LA, b, 49, 24, wp2 + 21 * 131072, b2 + 21 * 256,
                Y + (long)22 * 524288, tid);
  // group C: (k3,s2) then 7 x (k2,s1), L 49 -> 24 -> 17
  step<3, 1, 2>(LA, b, 24, 23, wp3 + 196608, b3 + 256, Y + (long)23 * 524288, tid);
#pragma unroll 1
  for (int l = 24; l < 30; ++l)
    step<2, 1, 2>(LA, b, 47 - l, 46 - l, wp2 + (l - 2) * 131072, b2 + (l - 2) * 256,
                  Y + (long)l * 524288, tid);
  step<2, 1, 0>(LA, b, 17, 0, wp2 + 28 * 131072, b2 + 28 * 256,
                Y + (long)30 * 524288, tid);
}

// ---- assemble: write the whole 256MB map coalesced, composing zeros/diag/stripes.
__global__ __launch_bounds__(256) void assemble_kernel(
    float* __restrict__ out, const float* __restrict__ x, const float* __restrict__ Y)
{
  const int f0 = blockIdx.x * 256 + threadIdx.x;   // 0 .. 524287
  const int c4 = f0 & 31, r = (f0 >> 5) & 127;
  const int bch0 = f0 >> 12;                        // advances +128 per iter

  int addr[4];
  bool dg[4];
#pragma unroll
  for (int jj = 0; jj < 4; ++jj) {
    int c = 4 * c4 + jj;
    int d = c - r;
    dg[jj] = (d == 0);
    int a = -1;
    if (d >= 1 && d <= 15) {
      a = (d - 1) * 524288 + r;
    } else if (d >= 17 && d <= 31 && (d & 1) == 1 && (r & 1) == 0) {
      a = (15 + ((d - 17) >> 1)) * 524288 + (r >> 1);
    } else if (d >= 35 && d <= 63 && (d & 3) == 3 && (r & 3) == 0) {
      a = (23 + ((d - 35) >> 2)) * 524288 + (r >> 2);
    }
    addr[jj] = a;
  }

  for (int it = 0; it < 32; ++it) {
    int bch = bch0 + it * 128;
    fvec4 v = {0.f, 0.f, 0.f, 0.f};
    int boff = bch * 128;
#pragma unroll
    for (int jj = 0; jj < 4; ++jj) {
      if (dg[jj])             v[jj] = x[boff + r];
      else if (addr[jj] >= 0) v[jj] = Y[addr[jj] + boff];
    }
    *reinterpret_cast<fvec4*>(out + (long)4 * (f0 + it * 524288)) = v;
  }
}

extern "C" void kernel_launch(void* const* d_in, const int* in_sizes, int n_in,
                              void* d_out, int out_size, void* d_ws, size_t ws_size,
                              hipStream_t stream)
{
  const float* x  = (const float*)d_in[0];
  const float* w2 = (const float*)d_in[1];
  const float* b2 = (const float*)d_in[2];
  const float* w3 = (const float*)d_in[3];
  const float* b3 = (const float*)d_in[4];
  float* out = (float*)d_out;
  unsigned short* ws = (unsigned short*)d_ws;
  float* Y = (float*)((char*)d_ws + Y_OFF_B);

  prep_kernel<<<4096, 256, 0, stream>>>(w2, w3, ws);
  chain_kernel<<<16, 1024, 0, stream>>>(x, b2, b3, ws, Y);
  assemble_kernel<<<2048, 256, 0, stream>>>(out, x, Y);
}

// Round 2
// 540.804 us; speedup vs baseline: 1.6425x; 1.6425x over previous
//
#include <hip/hip_runtime.h>

// ---- types ----
typedef __bf16 bf16x8 __attribute__((ext_vector_type(8)));
typedef float  floatx4 __attribute__((ext_vector_type(4)));
typedef float  fvec4  __attribute__((ext_vector_type(4)));
typedef unsigned short ushort4v __attribute__((ext_vector_type(4)));
typedef unsigned short ushort8v __attribute__((ext_vector_type(8)));

__device__ __forceinline__ unsigned short f2bf(float f) {
  unsigned int u = __float_as_uint(f);
  u = u + 0x7FFFu + ((u >> 16) & 1u);   // RNE
  return (unsigned short)(u >> 16);
}

// ws layout (byte offsets):
//   0        : WP2 bf16  (29 * 256 * 512)   = 7,602,176 B
//   7602176  : WP3 bf16  (2 * 256 * 768)    =   786,432 B
//   8388608  : X0 bf16   (16*256*128)       = 1,048,576 B, then pitched per-layer bf16 activ.
//   64 MiB   : Y fp32    [31][16*256][128]  = 65 MB compact stripe values
#define WP3_OFF   3801088    // ushort elems
#define X0_OFF    4194304    // ushort elems
#define Y_OFF_B   (64u << 20)

// ---- prep: fp32 -> bf16 copies (w2, w3, x0). Layout [o][i][k] == MFMA-B row order.
__global__ __launch_bounds__(256) void prep_kernel(
    const float* __restrict__ w2, const float* __restrict__ w3,
    const float* __restrict__ x, unsigned short* __restrict__ ws)
{
  int g = blockIdx.x * 256 + threadIdx.x;
  const float* src; unsigned short* dst;
  if (g < 950272)            { src = w2; dst = ws; }
  else if (g < 950272+98304) { g -= 950272; src = w3; dst = ws + WP3_OFF; }
  else                       { g -= (950272+98304); src = x; dst = ws + X0_OFF; }
  fvec4 v = *reinterpret_cast<const fvec4*>(src + 4*g);
  ushort4v o;
  o[0] = f2bf(v[0]); o[1] = f2bf(v[1]); o[2] = f2bf(v[2]); o[3] = f2bf(v[3]);
  *reinterpret_cast<ushort4v*>(dst + 4*g) = o;
}

// ---- conv layer: Y[b,n,m] = sum_{i,k} W[n,i,k]*X[b,i,cs*m+k] + bias[n]
// Writes compact bf16 (chain input) + compact fp32 (for assemble). No d_out traffic.
template<int KW>
__global__ __launch_bounds__(256) void conv_kernel(
    const unsigned short* __restrict__ Xin,   // [16*256][Lpin] bf16
    unsigned short* __restrict__ Xout,        // [16*256][Lpout] bf16
    const unsigned short* __restrict__ WP,    // [256][KS] bf16
    const float* __restrict__ bias,           // [256]
    float* __restrict__ Yl,                   // [16*256][128] fp32 compact (this layer)
    int Lin, int Lpin, int Lout, int Lpout)
{
  constexpr int CS   = (KW == 3) ? 2 : 1;
  constexpr int KS   = 256 * KW;
  constexpr int pitch = KS + 8;
  constexpr int NV   = (KW == 2) ? 5 : 9;
  __shared__ unsigned short LA[32 * pitch];

  const int tid = threadIdx.x;
  const int b   = blockIdx.z;
  const int m0  = blockIdx.x * 32;
  const int n0  = blockIdx.y * 64;

  // ---- stage A tile (vectorized row loads; tail garbage only feeds m>=Lout) ----
  {
    const int i = tid;
    const unsigned short* rp = Xin + ((b * 256 + i) * Lpin) + CS * m0;
    ushort8v xr[NV];
#pragma unroll
    for (int v = 0; v < NV; ++v)
      xr[v] = *reinterpret_cast<const ushort8v*>(rp + v * 8);
    const unsigned short* xs = reinterpret_cast<const unsigned short*>(xr);
    if (KW == 2) {
#pragma unroll
      for (int m = 0; m < 32; ++m) {
        unsigned int pk = (unsigned int)xs[m] | ((unsigned int)xs[m + 1] << 16);
        *reinterpret_cast<unsigned int*>(&LA[m * pitch + 2 * i]) = pk;
      }
    } else {
#pragma unroll
      for (int m = 0; m < 32; ++m) {
        int base = m * pitch + 3 * i;
        LA[base]     = xs[2 * m];
        LA[base + 1] = xs[2 * m + 1];
        LA[base + 2] = xs[2 * m + 2];
      }
    }
  }
  __syncthreads();

  const int wave = tid >> 6, lane = tid & 63;
  const int l15 = lane & 15, quad = lane >> 4;
  const int nn = n0 + wave * 16 + l15;
  const unsigned short* wrow = WP + (long)nn * KS;
  const int kbase = quad * 8;

  floatx4 acc0 = {0.f, 0.f, 0.f, 0.f};
  floatx4 acc1 = {0.f, 0.f, 0.f, 0.f};

  constexpr int niter = KS / 32;
#pragma unroll
  for (int kc = 0; kc < niter; ++kc) {
    int ko = kc * 32 + kbase;
    bf16x8 bfrag = *reinterpret_cast<const bf16x8*>(wrow + ko);
    bf16x8 a0 = *reinterpret_cast<const bf16x8*>(&LA[l15 * pitch + ko]);
    bf16x8 a1 = *reinterpret_cast<const bf16x8*>(&LA[(16 + l15) * pitch + ko]);
    acc0 = __builtin_amdgcn_mfma_f32_16x16x32_bf16(a0, bfrag, acc0, 0, 0, 0);
    acc1 = __builtin_amdgcn_mfma_f32_16x16x32_bf16(a1, bfrag, acc1, 0, 0, 0);
  }

  const float bv = bias[nn];
  const int row = b * 256 + nn;
  unsigned short* xo = Xout + row * Lpout;
  float* yo = Yl + row * 128;
#pragma unroll
  for (int r = 0; r < 4; ++r) {
    int m = m0 + quad * 4 + r;
    if (m < Lout) {
      float v = acc0[r] + bv;
      xo[m] = f2bf(v);
      yo[m] = v;
    }
    int m2 = m0 + 16 + quad * 4 + r;
    if (m2 < Lout) {
      float v = acc1[r] + bv;
      xo[m2] = f2bf(v);
      yo[m2] = v;
    }
  }
}

// ---- assemble v2: one block per (b,ch). Stage that (b,ch)'s ~2.4K stripe values
// (31 contiguous <=128-float runs of Y) + the diag x-row into LDS (pitch 129 ->
// the l-consecutive gather below is bank-conflict-free), then emit the 64KB
// [128][128] tile fully coalesced, selecting each element from LDS:
//   d==0 -> diag; 1<=d<=15 -> layer d-1, m=r; 17<=d<=31 odd, r even -> layer
//   15+(d-17)/2, m=r/2; 35<=d<=63 d%4==3, r%4==0 -> layer 23+(d-35)/4, m=r/4.
// (m < Lout automatic from c < 128 — proved offline.)
__global__ __launch_bounds__(256) void assemble_kernel(
    float* __restrict__ out, const float* __restrict__ x, const float* __restrict__ Y)
{
  __shared__ float S[32 * 129];
  const int blk = blockIdx.x;        // 0..4095 == b*256+ch
  const int tid = threadIdx.x;

  {
    const int m = tid & 127, half = tid >> 7;   // two layers staged per pass
#pragma unroll
    for (int lp = 0; lp < 16; ++lp) {
      const int l = lp * 2 + half;
      if (l < 31) {
        const int Lout = (l < 15) ? (127 - l)
                       : (l == 15) ? 56
                       : (l < 23)  ? (71 - l)
                       : (l == 23) ? 24 : (47 - l);
        if (m < Lout) S[l * 129 + m] = Y[(long)l * 524288 + blk * 128 + m];
      } else {
        S[31 * 129 + m] = x[blk * 128 + m];
      }
    }
  }
  __syncthreads();

  const long obase = (long)blk << 14;
#pragma unroll 1
  for (int it = 0; it < 16; ++it) {
    const int flat = it * 256 + tid;          // fvec4 index in the 128x128 tile
    const int r = flat >> 5, c0 = (flat & 31) << 2;
    fvec4 v = {0.f, 0.f, 0.f, 0.f};
#pragma unroll
    for (int jj = 0; jj < 4; ++jj) {
      const int d = c0 + jj - r;
      if (d == 0)                 v[jj] = S[31 * 129 + r];
      else if (d >= 1 && d <= 15) v[jj] = S[(d - 1) * 129 + r];
      else if (d >= 17 && d <= 31 && (d & 1) == 1 && (r & 1) == 0)
        v[jj] = S[(15 + ((d - 17) >> 1)) * 129 + (r >> 1)];
      else if (d >= 35 && d <= 63 && (d & 3) == 3 && (r & 3) == 0)
        v[jj] = S[(23 + ((d - 35) >> 2)) * 129 + (r >> 2)];
    }
    *reinterpret_cast<fvec4*>(out + obase + 4 * flat) = v;
  }
}

extern "C" void kernel_launch(void* const* d_in, const int* in_sizes, int n_in,
                              void* d_out, int out_size, void* d_ws, size_t ws_size,
                              hipStream_t stream)
{
  const float* x  = (const float*)d_in[0];
  const float* w2 = (const float*)d_in[1];
  const float* b2 = (const float*)d_in[2];
  const float* w3 = (const float*)d_in[3];
  const float* b3 = (const float*)d_in[4];
  float* out = (float*)d_out;
  unsigned short* ws = (unsigned short*)d_ws;
  float* Y = (float*)((char*)d_ws + Y_OFF_B);

  prep_kernel<<<4608, 256, 0, stream>>>(w2, w3, x, ws);

  const int counts[3] = {15, 8, 8};
  int stride = 1, offset = 0;
  int Lin = 128, Lpin = 128;
  int c2 = 0, c3 = 0, lidx = 0;
  long xprev = X0_OFF;
  long xnext = xprev + (long)16 * 256 * 128 + 64;
  for (int ci = 0; ci < 3; ++ci) {
    for (int k = 0; k < counts[ci]; ++k) {
      offset += stride;
      int KW = (ci > 0 && k == 0) ? 3 : 2;
      int cs = (KW == 3) ? 2 : 1;
      int Lout = (Lin - KW) / cs + 1;
      int Lpout = (Lout + 7) & ~7;
      const unsigned short* WPt; const float* bt;
      if (KW == 2) { WPt = ws + (long)c2 * 131072; bt = b2 + c2 * 256; ++c2; }
      else         { WPt = ws + WP3_OFF + (long)c3 * 196608; bt = b3 + c3 * 256; ++c3; }
      dim3 grid((Lout + 31) / 32, 4, 16);
      if (KW == 2)
        conv_kernel<2><<<grid, 256, 0, stream>>>(
            ws + xprev, ws + xnext, WPt, bt, Y + (long)lidx * 524288,
            Lin, Lpin, Lout, Lpout);
      else
        conv_kernel<3><<<grid, 256, 0, stream>>>(
            ws + xprev, ws + xnext, WPt, bt, Y + (long)lidx * 524288,
            Lin, Lpin, Lout, Lpout);
      ++lidx;
      xprev = xnext;
      xnext += (long)16 * 256 * Lpout + 64;
      Lin = Lout; Lpin = Lpout;
    }
    stride *= 2;
  }

  assemble_kernel<<<4096, 256, 0, stream>>>(out, x, Y);
}